// Round 3
// baseline (405.823 us; speedup 1.0000x reference)
//
#include <hip/hip_runtime.h>
#include <stdint.h>

#define NW 741
#define NEG_INF_KEY 0x007FFFFFu  // key(-inf); real finite scores map strictly above

typedef float f2 __attribute__((ext_vector_type(2)));

static __device__ __forceinline__ unsigned score_key(float f) {
  const unsigned u = __float_as_uint(f);
  return (u & 0x80000000u) ? ~u : (u | 0x80000000u);
}
static __device__ __forceinline__ float key_score(unsigned k) {
  return __uint_as_float((k & 0x80000000u) ? (k ^ 0x80000000u) : ~k);
}

// Wave argmax (tie -> lowest index): max-reduce + readlane + masked
// min-index-reduce. Identical semantics to greedy NMS argmax.
template<int CTRL>
static __device__ __forceinline__ unsigned max_step(unsigned m) {
  const unsigned t = (unsigned)__builtin_amdgcn_update_dpp(0, (int)m, CTRL, 0xF, 0xF, true);
  return m > t ? m : t;
}
template<int CTRL>
static __device__ __forceinline__ int min_step(int c) {
  const int t = __builtin_amdgcn_update_dpp(0x7fffffff, c, CTRL, 0xF, 0xF, false);
  return c < t ? c : t;
}
static __device__ __forceinline__ void wave_argmax(unsigned& k, int& i) {
  unsigned m = k;
  m = max_step<0x111>(m);
  m = max_step<0x112>(m);
  m = max_step<0x114>(m);
  m = max_step<0x118>(m);
  m = max_step<0x142>(m);
  m = max_step<0x143>(m);
  const unsigned smax = (unsigned)__builtin_amdgcn_readlane((int)m, 63);
  int ci = (k == smax) ? i : 0x7fffffff;
  ci = min_step<0x111>(ci);
  ci = min_step<0x112>(ci);
  ci = min_step<0x114>(ci);
  ci = min_step<0x118>(ci);
  ci = min_step<0x142>(ci);
  ci = min_step<0x143>(ci);
  k = smax;
  i = __builtin_amdgcn_readlane(ci, 63);
}

// One 64-window slot of one ratio, both images. Bit-exact chained row-major
// fp32 window sum (zero-init, += each element in order), IEEE fp32 div —
// byte-identical arithmetic to the R2 kernel that passed. Keys are returned
// into NAMED SCALARS (no local array, no pointer aliasing -> no scratch).
template<int H, int W, int OFF, int S0>
static __device__ __forceinline__ void slot2(const f2* __restrict__ im2,
                                             float* __restrict__ wrowA,
                                             float* __restrict__ wrowB,
                                             const int lane, const bool hasB,
                                             unsigned& ka, unsigned& kb) {
  constexpr int Wo = 14 - W + 1;
  constexpr int NWIN = (14 - H + 1) * Wo;
  const int o = S0 + lane;
  ka = 0u; kb = 0u;
  if (o < NWIN) {
    const int i = o / Wo, j = o - i * Wo;
    const f2* p = im2 + (i * 14 + j);
    f2 acc = {0.0f, 0.0f};
#pragma unroll
    for (int di = 0; di < H; ++di)
#pragma unroll
      for (int dj = 0; dj < W; ++dj)
        acc += p[di * 14 + dj];           // ds_read_b64, chained adds
    const float scA = acc.x / (float)(H * W);
    const float scB = acc.y / (float)(H * W);
    wrowA[OFF + o] = scA;
    if (hasB) wrowB[OFF + o] = scB;
    ka = score_key(scA);
    kb = score_key(scB);
  }
}

// Suppression of one slot for both images. bA/aA/bB/aB must be in scope.
// Exact compare 4*inter > union  <=>  iou > 0.25 (integers < 2^24, fp32-exact).
#define SUP2(KA, KB, SB) {                                          \
    const float4 cb = c_box[(SB) + lane];                           \
    const float ar = (cb.z - cb.x + 1.0f) * (cb.w - cb.y + 1.0f);   \
    float lx = fminf(cb.z, bA.z) - fmaxf(cb.x, bA.x) + 1.0f;        \
    float ly = fminf(cb.w, bA.w) - fmaxf(cb.y, bA.y) + 1.0f;        \
    float in = (lx < 0.0f || ly < 0.0f) ? 0.0f : lx * ly;           \
    if (4.0f * in > ar + aA - in) KA = 0u;                          \
    lx = fminf(cb.z, bB.z) - fmaxf(cb.x, bB.x) + 1.0f;              \
    ly = fminf(cb.w, bB.w) - fmaxf(cb.y, bB.y) + 1.0f;              \
    in = (lx < 0.0f || ly < 0.0f) ? 0.0f : lx * ly;                 \
    if (4.0f * in > ar + aB - in) KB = 0u; }

// 6-slot per-lane scan (tie -> lowest index via ascending bases + strict >).
#define SCAN6(bk, bi, K0, K1, K2, K3, K4, K5, S0, S1, S2, S3, S4, S5) \
    bk = K0; bi = (S0) + lane;                                        \
    if (K1 > bk) { bk = K1; bi = (S1) + lane; }                       \
    if (K2 > bk) { bk = K2; bi = (S2) + lane; }                       \
    if (K3 > bk) { bk = K3; bi = (S3) + lane; }                       \
    if (K4 > bk) { bk = K4; bi = (S4) + lane; }                       \
    if (K5 > bk) { bk = K5; bi = (S5) + lane; }

#define SELPICK(bk, bi, last, lastS, idx, sc)                 \
    if (bk > NEG_INF_KEY) { idx = bi; sc = key_score(bk); }   \
    else { idx = last; sc = lastS; }                          \
    last = idx; lastS = sc;

__global__ __launch_bounds__(256, 8) void appm_kernel(
    const float* __restrict__ x, const int* __restrict__ coords,
    float* __restrict__ out, int B) {

  __shared__ float4 c_box[NW];      // 11856 B
  __shared__ f2 imgp[4][196];       // 6272 B: per wave, 196 x {imgA, imgB}
  // LDS total 18128 B -> 8 blocks/CU (2048 threads)

  const int t = threadIdx.x;
  const int wv = t >> 6;
  const int lane = t & 63;
  const int img0 = blockIdx.x * 8;
  const int imgA = img0 + wv * 2;
  const int imgB = imgA + 1;
  const bool hasA = (imgA < B);
  const bool hasB = (imgB < B);

  // ---- Phase A: coord table (float4 box), shared per block ----
  for (int w = t; w < NW; w += 256) {
    const int4 c = ((const int4*)coords)[w];
    c_box[w] = make_float4((float)c.x, (float)c.y, (float)c.z, (float)c.w);
  }

  // ---- Phase B: stage 8 images as 4 pair-interleaved f2 planes ----
  {
    int nimg = B - img0; if (nimg > 8) nimg = 8;
    const float* xb = x + (long long)img0 * 196;
    for (int u = t; u < 784; u += 256) {        // 784 = 4 pairs * 196
      const int pr = u / 196, k = u - pr * 196;
      const int iA = 2 * pr, iB = iA + 1;
      f2 v;
      v.x = (iA < nimg) ? xb[iA * 196 + k] : 0.0f;
      v.y = (iB < nimg) ? xb[iB * 196 + k] : 0.0f;
      imgp[pr][k] = v;                          // ds_write_b64, dense
    }
  }
  __syncthreads();

  if (hasA) {
    const f2* im2 = imgp[wv];
    float* wrowA = out + (long long)B * 12 + (long long)imgA * NW;
    float* wrowB = wrowA + NW;

    // ---- Phase C: 741 window scores; keys in NAMED scalar VGPRs ----
    // Group 1 slots (bases 0,64,121,185,241,305):
    unsigned kA0, kA1, kA2, kA3, kA4, kA5, kB0, kB1, kB2, kB3, kB4, kB5;
    slot2<4, 4, 0, 0>(im2, wrowA, wrowB, lane, hasB, kA0, kB0);
    slot2<4, 4, 0, 64>(im2, wrowA, wrowB, lane, hasB, kA1, kB1);
    slot2<3, 5, 121, 0>(im2, wrowA, wrowB, lane, hasB, kA2, kB2);
    slot2<3, 5, 121, 64>(im2, wrowA, wrowB, lane, hasB, kA3, kB3);
    slot2<5, 3, 241, 0>(im2, wrowA, wrowB, lane, hasB, kA4, kB4);
    slot2<5, 3, 241, 64>(im2, wrowA, wrowB, lane, hasB, kA5, kB5);
    // Group 2 slots (bases 361,425,442,506,522,586):
    unsigned kA6, kA7, kA8, kA9, kA10, kA11, kB6, kB7, kB8, kB9, kB10, kB11;
    slot2<6, 6, 361, 0>(im2, wrowA, wrowB, lane, hasB, kA6, kB6);
    slot2<6, 6, 361, 64>(im2, wrowA, wrowB, lane, hasB, kA7, kB7);
    slot2<5, 7, 442, 0>(im2, wrowA, wrowB, lane, hasB, kA8, kB8);
    slot2<5, 7, 442, 64>(im2, wrowA, wrowB, lane, hasB, kA9, kB9);
    slot2<7, 5, 522, 0>(im2, wrowA, wrowB, lane, hasB, kA10, kB10);
    slot2<7, 5, 522, 64>(im2, wrowA, wrowB, lane, hasB, kA11, kB11);
    // Group 3 (N=1, no suppression): fold argmax on the fly, store no keys.
    unsigned tA, tB;
    slot2<8, 8, 602, 0>(im2, wrowA, wrowB, lane, hasB, tA, tB);
    unsigned gkA = tA, gkB = tB;
    int giA = 602 + lane, giB = 602 + lane;
    slot2<6, 10, 651, 0>(im2, wrowA, wrowB, lane, hasB, tA, tB);
    if (tA > gkA) { gkA = tA; giA = 651 + lane; }
    if (tB > gkB) { gkB = tB; giB = 651 + lane; }
    slot2<10, 6, 696, 0>(im2, wrowA, wrowB, lane, hasB, tA, tB);
    if (tA > gkA) { gkA = tA; giA = 696 + lane; }
    if (tB > gkB) { gkB = tB; giB = 696 + lane; }

    // ---- Phase D: greedy NMS, all keys register-resident ----
    float myIA = 0.0f, mySA = 0.0f, myIB = 0.0f, mySB = 0.0f;
    unsigned bkA, bkB; int biA, biB;
    int idxA, idxB; float scA, scB;

    // ===== Group 1 (windows 0..361, N=3) =====
    {
      int lastA = 0, lastB = 0; float lastSA = 0.0f, lastSB = 0.0f;
      // pick 0
      SCAN6(bkA, biA, kA0, kA1, kA2, kA3, kA4, kA5, 0, 64, 121, 185, 241, 305);
      SCAN6(bkB, biB, kB0, kB1, kB2, kB3, kB4, kB5, 0, 64, 121, 185, 241, 305);
      wave_argmax(bkA, biA); wave_argmax(bkB, biB);
      SELPICK(bkA, biA, lastA, lastSA, idxA, scA);
      SELPICK(bkB, biB, lastB, lastSB, idxB, scB);
      if (lane == 0) { myIA = (float)idxA; mySA = scA; myIB = (float)idxB; mySB = scB; }
      {
        const float4 bA = c_box[idxA]; const float4 bB = c_box[idxB];
        const float aA = (bA.z - bA.x + 1.0f) * (bA.w - bA.y + 1.0f);
        const float aB = (bB.z - bB.x + 1.0f) * (bB.w - bB.y + 1.0f);
        SUP2(kA0, kB0, 0); SUP2(kA1, kB1, 64); SUP2(kA2, kB2, 121);
        SUP2(kA3, kB3, 185); SUP2(kA4, kB4, 241); SUP2(kA5, kB5, 305);
      }
      // pick 1
      SCAN6(bkA, biA, kA0, kA1, kA2, kA3, kA4, kA5, 0, 64, 121, 185, 241, 305);
      SCAN6(bkB, biB, kB0, kB1, kB2, kB3, kB4, kB5, 0, 64, 121, 185, 241, 305);
      wave_argmax(bkA, biA); wave_argmax(bkB, biB);
      SELPICK(bkA, biA, lastA, lastSA, idxA, scA);
      SELPICK(bkB, biB, lastB, lastSB, idxB, scB);
      if (lane == 1) { myIA = (float)idxA; mySA = scA; myIB = (float)idxB; mySB = scB; }
      {
        const float4 bA = c_box[idxA]; const float4 bB = c_box[idxB];
        const float aA = (bA.z - bA.x + 1.0f) * (bA.w - bA.y + 1.0f);
        const float aB = (bB.z - bB.x + 1.0f) * (bB.w - bB.y + 1.0f);
        SUP2(kA0, kB0, 0); SUP2(kA1, kB1, 64); SUP2(kA2, kB2, 121);
        SUP2(kA3, kB3, 185); SUP2(kA4, kB4, 241); SUP2(kA5, kB5, 305);
      }
      // pick 2 (no suppression after)
      SCAN6(bkA, biA, kA0, kA1, kA2, kA3, kA4, kA5, 0, 64, 121, 185, 241, 305);
      SCAN6(bkB, biB, kB0, kB1, kB2, kB3, kB4, kB5, 0, 64, 121, 185, 241, 305);
      wave_argmax(bkA, biA); wave_argmax(bkB, biB);
      SELPICK(bkA, biA, lastA, lastSA, idxA, scA);
      SELPICK(bkB, biB, lastB, lastSB, idxB, scB);
      if (lane == 2) { myIA = (float)idxA; mySA = scA; myIB = (float)idxB; mySB = scB; }
    }

    // ===== Group 2 (windows 361..602, N=2) =====
    {
      int lastA = 361, lastB = 361; float lastSA = 0.0f, lastSB = 0.0f;
      // pick 3
      SCAN6(bkA, biA, kA6, kA7, kA8, kA9, kA10, kA11, 361, 425, 442, 506, 522, 586);
      SCAN6(bkB, biB, kB6, kB7, kB8, kB9, kB10, kB11, 361, 425, 442, 506, 522, 586);
      wave_argmax(bkA, biA); wave_argmax(bkB, biB);
      SELPICK(bkA, biA, lastA, lastSA, idxA, scA);
      SELPICK(bkB, biB, lastB, lastSB, idxB, scB);
      if (lane == 3) { myIA = (float)idxA; mySA = scA; myIB = (float)idxB; mySB = scB; }
      {
        const float4 bA = c_box[idxA]; const float4 bB = c_box[idxB];
        const float aA = (bA.z - bA.x + 1.0f) * (bA.w - bA.y + 1.0f);
        const float aB = (bB.z - bB.x + 1.0f) * (bB.w - bB.y + 1.0f);
        SUP2(kA6, kB6, 361); SUP2(kA7, kB7, 425); SUP2(kA8, kB8, 442);
        SUP2(kA9, kB9, 506); SUP2(kA10, kB10, 522); SUP2(kA11, kB11, 586);
      }
      // pick 4 (no suppression after)
      SCAN6(bkA, biA, kA6, kA7, kA8, kA9, kA10, kA11, 361, 425, 442, 506, 522, 586);
      SCAN6(bkB, biB, kB6, kB7, kB8, kB9, kB10, kB11, 361, 425, 442, 506, 522, 586);
      wave_argmax(bkA, biA); wave_argmax(bkB, biB);
      SELPICK(bkA, biA, lastA, lastSA, idxA, scA);
      SELPICK(bkB, biB, lastB, lastSB, idxB, scB);
      if (lane == 4) { myIA = (float)idxA; mySA = scA; myIB = (float)idxB; mySB = scB; }
    }

    // ===== Group 3 (windows 602..741, N=1) — argmax precomputed =====
    {
      wave_argmax(gkA, giA); wave_argmax(gkB, giB);
      if (gkA > NEG_INF_KEY) { idxA = giA; scA = key_score(gkA); }
      else { idxA = 602; scA = 0.0f; }
      if (gkB > NEG_INF_KEY) { idxB = giB; scB = key_score(gkB); }
      else { idxB = 602; scB = 0.0f; }
      if (lane == 5) { myIA = (float)idxA; mySA = scA; myIB = (float)idxB; mySB = scB; }
    }

    // ---- outputs ----
    if (lane < 6) {
      const long long a6 = (long long)imgA * 6 + lane;
      out[a6] = myIA;
      out[(long long)B * 6 + a6] = mySA;
      if (hasB) {
        const long long b6 = (long long)imgB * 6 + lane;
        out[b6] = myIB;
        out[(long long)B * 6 + b6] = mySB;
      }
    }
  }
}

extern "C" void kernel_launch(void* const* d_in, const int* in_sizes, int n_in,
                              void* d_out, int out_size, void* d_ws, size_t ws_size,
                              hipStream_t stream) {
  const float* x = (const float*)d_in[0];
  const int* coords = (const int*)d_in[1];
  float* out = (float*)d_out;
  const int B = in_sizes[0] / 196;
  const int nblk = (B + 7) / 8;
  appm_kernel<<<dim3(nblk), dim3(256), 0, stream>>>(x, coords, out, B);
}

// Round 4
// 384.855 us; speedup vs baseline: 1.0545x; 1.0545x over previous
//
#include <hip/hip_runtime.h>
#include <stdint.h>

#define NW 741
#define NEG_INF_KEY 0x007FFFFFu  // key(-inf); real finite scores map strictly above

typedef float f2 __attribute__((ext_vector_type(2)));

static __device__ __forceinline__ unsigned score_key(float f) {
  const unsigned u = __float_as_uint(f);
  return (u & 0x80000000u) ? ~u : (u | 0x80000000u);
}
static __device__ __forceinline__ float key_score(unsigned k) {
  return __uint_as_float((k & 0x80000000u) ? (k ^ 0x80000000u) : ~k);
}

// Wave argmax (tie -> lowest index): max-reduce + readlane + masked
// min-index-reduce. Identical semantics to greedy NMS argmax.
template<int CTRL>
static __device__ __forceinline__ unsigned max_step(unsigned m) {
  const unsigned t = (unsigned)__builtin_amdgcn_update_dpp(0, (int)m, CTRL, 0xF, 0xF, true);
  return m > t ? m : t;
}
template<int CTRL>
static __device__ __forceinline__ int min_step(int c) {
  const int t = __builtin_amdgcn_update_dpp(0x7fffffff, c, CTRL, 0xF, 0xF, false);
  return c < t ? c : t;
}
static __device__ __forceinline__ void wave_argmax(unsigned& k, int& i) {
  unsigned m = k;
  m = max_step<0x111>(m);
  m = max_step<0x112>(m);
  m = max_step<0x114>(m);
  m = max_step<0x118>(m);
  m = max_step<0x142>(m);
  m = max_step<0x143>(m);
  const unsigned smax = (unsigned)__builtin_amdgcn_readlane((int)m, 63);
  int ci = (k == smax) ? i : 0x7fffffff;
  ci = min_step<0x111>(ci);
  ci = min_step<0x112>(ci);
  ci = min_step<0x114>(ci);
  ci = min_step<0x118>(ci);
  ci = min_step<0x142>(ci);
  ci = min_step<0x143>(ci);
  k = smax;
  i = __builtin_amdgcn_readlane(ci, 63);
}

// One 64-window slot of one ratio, both images. Bit-exact chained row-major
// fp32 window sum (zero-init, += each element in (di,dj) order), IEEE fp32
// div — byte-identical arithmetic to the R2/R3 kernels that passed.
template<int H, int W, int OFF, int S0>
static __device__ __forceinline__ void slot2(const f2* __restrict__ im2,
                                             float* __restrict__ wrowA,
                                             float* __restrict__ wrowB,
                                             const int lane, const bool hasB,
                                             unsigned& ka, unsigned& kb) {
  constexpr int Wo = 14 - W + 1;
  constexpr int NWIN = (14 - H + 1) * Wo;
  const int o = S0 + lane;
  ka = 0u; kb = 0u;
  if (o < NWIN) {
    const int i = o / Wo, j = o - i * Wo;
    const f2* p = im2 + (i * 14 + j);
    f2 acc = {0.0f, 0.0f};
#pragma unroll
    for (int di = 0; di < H; ++di)
#pragma unroll
      for (int dj = 0; dj < W; ++dj)
        acc += p[di * 14 + dj];           // ds_read_b64, chained adds
    const float scA = acc.x / (float)(H * W);
    const float scB = acc.y / (float)(H * W);
    wrowA[OFF + o] = scA;
    if (hasB) wrowB[OFF + o] = scB;
    ka = score_key(scA);
    kb = score_key(scB);
  }
}

// Suppression of one slot for both images. bA/aA/bB/aB must be in scope.
// Exact compare 4*inter > union  <=>  iou > 0.25 (integers < 2^24, fp32-exact).
#define SUP2(KA, KB, SB) {                                          \
    const float4 cb = c_box[(SB) + lane];                           \
    const float ar = (cb.z - cb.x + 1.0f) * (cb.w - cb.y + 1.0f);   \
    float lx = fminf(cb.z, bA.z) - fmaxf(cb.x, bA.x) + 1.0f;        \
    float ly = fminf(cb.w, bA.w) - fmaxf(cb.y, bA.y) + 1.0f;        \
    float in = (lx < 0.0f || ly < 0.0f) ? 0.0f : lx * ly;           \
    if (4.0f * in > ar + aA - in) KA = 0u;                          \
    lx = fminf(cb.z, bB.z) - fmaxf(cb.x, bB.x) + 1.0f;              \
    ly = fminf(cb.w, bB.w) - fmaxf(cb.y, bB.y) + 1.0f;              \
    in = (lx < 0.0f || ly < 0.0f) ? 0.0f : lx * ly;                 \
    if (4.0f * in > ar + aB - in) KB = 0u; }

// 6-slot per-lane scan (tie -> lowest index via ascending bases + strict >).
#define SCAN6(bk, bi, K0, K1, K2, K3, K4, K5, S0, S1, S2, S3, S4, S5) \
    bk = K0; bi = (S0) + lane;                                        \
    if (K1 > bk) { bk = K1; bi = (S1) + lane; }                       \
    if (K2 > bk) { bk = K2; bi = (S2) + lane; }                       \
    if (K3 > bk) { bk = K3; bi = (S3) + lane; }                       \
    if (K4 > bk) { bk = K4; bi = (S4) + lane; }                       \
    if (K5 > bk) { bk = K5; bi = (S5) + lane; }

#define SELPICK(bk, bi, last, lastS, idx, sc)                 \
    if (bk > NEG_INF_KEY) { idx = bi; sc = key_score(bk); }   \
    else { idx = last; sc = lastS; }                          \
    last = idx; lastS = sc;

__global__ __launch_bounds__(256, 4) void appm_kernel(
    const float* __restrict__ x, const int* __restrict__ coords,
    float* __restrict__ out, int B) {

  __shared__ float4 c_box[NW];      // 11856 B
  __shared__ f2 imgp[4][196];       // 6272 B: per wave, 196 x {imgA, imgB}
  // LDS total 18128 B -> 8 blocks/CU possible; actual occupancy set by VGPRs.
  // NOTE: launch_bounds(...,8) empirically caps arch VGPRs at 32 on this
  // toolchain (R2/R3: VGPR_Count=32 + heavy scratch). (...,4) gave natural
  // allocation (R1: 52 VGPR, zero scratch). Keep 4; need actual <=64.

  const int t = threadIdx.x;
  const int wv = t >> 6;
  const int lane = t & 63;
  const int img0 = blockIdx.x * 8;
  const int imgA = img0 + wv * 2;
  const int imgB = imgA + 1;
  const bool hasA = (imgA < B);
  const bool hasB = (imgB < B);

  // ---- Phase A: coord table (float4 box), shared per block ----
  for (int w = t; w < NW; w += 256) {
    const int4 c = ((const int4*)coords)[w];
    c_box[w] = make_float4((float)c.x, (float)c.y, (float)c.z, (float)c.w);
  }

  // ---- Phase B: stage 8 images as 4 pair-interleaved f2 planes ----
  {
    int nimg = B - img0; if (nimg > 8) nimg = 8;
    const float* xb = x + (long long)img0 * 196;
    for (int u = t; u < 784; u += 256) {        // 784 = 4 pairs * 196
      const int pr = u / 196, k = u - pr * 196;
      const int iA = 2 * pr, iB = iA + 1;
      f2 v;
      v.x = (iA < nimg) ? xb[iA * 196 + k] : 0.0f;
      v.y = (iB < nimg) ? xb[iB * 196 + k] : 0.0f;
      imgp[pr][k] = v;                          // ds_write_b64, dense
    }
  }
  __syncthreads();

  if (hasA) {
    const f2* im2 = imgp[wv];
    float* wrowA = out + (long long)B * 12 + (long long)imgA * NW;
    float* wrowB = wrowA + NW;

    float myIA = 0.0f, mySA = 0.0f, myIB = 0.0f, mySB = 0.0f;
    unsigned bkA, bkB; int biA, biB;
    int idxA, idxB; float scA, scB;

    // ===== Group 1 (windows 0..361, N=3): score -> NMS -> release regs =====
    {
      unsigned kA0, kA1, kA2, kA3, kA4, kA5, kB0, kB1, kB2, kB3, kB4, kB5;
      slot2<4, 4, 0, 0>(im2, wrowA, wrowB, lane, hasB, kA0, kB0);
      slot2<4, 4, 0, 64>(im2, wrowA, wrowB, lane, hasB, kA1, kB1);
      slot2<3, 5, 121, 0>(im2, wrowA, wrowB, lane, hasB, kA2, kB2);
      slot2<3, 5, 121, 64>(im2, wrowA, wrowB, lane, hasB, kA3, kB3);
      slot2<5, 3, 241, 0>(im2, wrowA, wrowB, lane, hasB, kA4, kB4);
      slot2<5, 3, 241, 64>(im2, wrowA, wrowB, lane, hasB, kA5, kB5);

      int lastA = 0, lastB = 0; float lastSA = 0.0f, lastSB = 0.0f;
      // pick 0
      SCAN6(bkA, biA, kA0, kA1, kA2, kA3, kA4, kA5, 0, 64, 121, 185, 241, 305);
      SCAN6(bkB, biB, kB0, kB1, kB2, kB3, kB4, kB5, 0, 64, 121, 185, 241, 305);
      wave_argmax(bkA, biA); wave_argmax(bkB, biB);
      SELPICK(bkA, biA, lastA, lastSA, idxA, scA);
      SELPICK(bkB, biB, lastB, lastSB, idxB, scB);
      if (lane == 0) { myIA = (float)idxA; mySA = scA; myIB = (float)idxB; mySB = scB; }
      {
        const float4 bA = c_box[idxA]; const float4 bB = c_box[idxB];
        const float aA = (bA.z - bA.x + 1.0f) * (bA.w - bA.y + 1.0f);
        const float aB = (bB.z - bB.x + 1.0f) * (bB.w - bB.y + 1.0f);
        SUP2(kA0, kB0, 0); SUP2(kA1, kB1, 64); SUP2(kA2, kB2, 121);
        SUP2(kA3, kB3, 185); SUP2(kA4, kB4, 241); SUP2(kA5, kB5, 305);
      }
      // pick 1
      SCAN6(bkA, biA, kA0, kA1, kA2, kA3, kA4, kA5, 0, 64, 121, 185, 241, 305);
      SCAN6(bkB, biB, kB0, kB1, kB2, kB3, kB4, kB5, 0, 64, 121, 185, 241, 305);
      wave_argmax(bkA, biA); wave_argmax(bkB, biB);
      SELPICK(bkA, biA, lastA, lastSA, idxA, scA);
      SELPICK(bkB, biB, lastB, lastSB, idxB, scB);
      if (lane == 1) { myIA = (float)idxA; mySA = scA; myIB = (float)idxB; mySB = scB; }
      {
        const float4 bA = c_box[idxA]; const float4 bB = c_box[idxB];
        const float aA = (bA.z - bA.x + 1.0f) * (bA.w - bA.y + 1.0f);
        const float aB = (bB.z - bB.x + 1.0f) * (bB.w - bB.y + 1.0f);
        SUP2(kA0, kB0, 0); SUP2(kA1, kB1, 64); SUP2(kA2, kB2, 121);
        SUP2(kA3, kB3, 185); SUP2(kA4, kB4, 241); SUP2(kA5, kB5, 305);
      }
      // pick 2 (no suppression after)
      SCAN6(bkA, biA, kA0, kA1, kA2, kA3, kA4, kA5, 0, 64, 121, 185, 241, 305);
      SCAN6(bkB, biB, kB0, kB1, kB2, kB3, kB4, kB5, 0, 64, 121, 185, 241, 305);
      wave_argmax(bkA, biA); wave_argmax(bkB, biB);
      SELPICK(bkA, biA, lastA, lastSA, idxA, scA);
      SELPICK(bkB, biB, lastB, lastSB, idxB, scB);
      if (lane == 2) { myIA = (float)idxA; mySA = scA; myIB = (float)idxB; mySB = scB; }
    }

    // ===== Group 2 (windows 361..602, N=2): score -> NMS -> release =====
    {
      unsigned kA6, kA7, kA8, kA9, kA10, kA11, kB6, kB7, kB8, kB9, kB10, kB11;
      slot2<6, 6, 361, 0>(im2, wrowA, wrowB, lane, hasB, kA6, kB6);
      slot2<6, 6, 361, 64>(im2, wrowA, wrowB, lane, hasB, kA7, kB7);
      slot2<5, 7, 442, 0>(im2, wrowA, wrowB, lane, hasB, kA8, kB8);
      slot2<5, 7, 442, 64>(im2, wrowA, wrowB, lane, hasB, kA9, kB9);
      slot2<7, 5, 522, 0>(im2, wrowA, wrowB, lane, hasB, kA10, kB10);
      slot2<7, 5, 522, 64>(im2, wrowA, wrowB, lane, hasB, kA11, kB11);

      int lastA = 361, lastB = 361; float lastSA = 0.0f, lastSB = 0.0f;
      // pick 3
      SCAN6(bkA, biA, kA6, kA7, kA8, kA9, kA10, kA11, 361, 425, 442, 506, 522, 586);
      SCAN6(bkB, biB, kB6, kB7, kB8, kB9, kB10, kB11, 361, 425, 442, 506, 522, 586);
      wave_argmax(bkA, biA); wave_argmax(bkB, biB);
      SELPICK(bkA, biA, lastA, lastSA, idxA, scA);
      SELPICK(bkB, biB, lastB, lastSB, idxB, scB);
      if (lane == 3) { myIA = (float)idxA; mySA = scA; myIB = (float)idxB; mySB = scB; }
      {
        const float4 bA = c_box[idxA]; const float4 bB = c_box[idxB];
        const float aA = (bA.z - bA.x + 1.0f) * (bA.w - bA.y + 1.0f);
        const float aB = (bB.z - bB.x + 1.0f) * (bB.w - bB.y + 1.0f);
        SUP2(kA6, kB6, 361); SUP2(kA7, kB7, 425); SUP2(kA8, kB8, 442);
        SUP2(kA9, kB9, 506); SUP2(kA10, kB10, 522); SUP2(kA11, kB11, 586);
      }
      // pick 4 (no suppression after)
      SCAN6(bkA, biA, kA6, kA7, kA8, kA9, kA10, kA11, 361, 425, 442, 506, 522, 586);
      SCAN6(bkB, biB, kB6, kB7, kB8, kB9, kB10, kB11, 361, 425, 442, 506, 522, 586);
      wave_argmax(bkA, biA); wave_argmax(bkB, biB);
      SELPICK(bkA, biA, lastA, lastSA, idxA, scA);
      SELPICK(bkB, biB, lastB, lastSB, idxB, scB);
      if (lane == 4) { myIA = (float)idxA; mySA = scA; myIB = (float)idxB; mySB = scB; }
    }

    // ===== Group 3 (windows 602..741, N=1): running argmax, no key storage =====
    {
      unsigned tA, tB;
      slot2<8, 8, 602, 0>(im2, wrowA, wrowB, lane, hasB, tA, tB);
      unsigned gkA = tA, gkB = tB;
      int giA = 602 + lane, giB = 602 + lane;
      slot2<6, 10, 651, 0>(im2, wrowA, wrowB, lane, hasB, tA, tB);
      if (tA > gkA) { gkA = tA; giA = 651 + lane; }
      if (tB > gkB) { gkB = tB; giB = 651 + lane; }
      slot2<10, 6, 696, 0>(im2, wrowA, wrowB, lane, hasB, tA, tB);
      if (tA > gkA) { gkA = tA; giA = 696 + lane; }
      if (tB > gkB) { gkB = tB; giB = 696 + lane; }

      wave_argmax(gkA, giA); wave_argmax(gkB, giB);
      if (gkA > NEG_INF_KEY) { idxA = giA; scA = key_score(gkA); }
      else { idxA = 602; scA = 0.0f; }
      if (gkB > NEG_INF_KEY) { idxB = giB; scB = key_score(gkB); }
      else { idxB = 602; scB = 0.0f; }
      if (lane == 5) { myIA = (float)idxA; mySA = scA; myIB = (float)idxB; mySB = scB; }
    }

    // ---- outputs ----
    if (lane < 6) {
      const long long a6 = (long long)imgA * 6 + lane;
      out[a6] = myIA;
      out[(long long)B * 6 + a6] = mySA;
      if (hasB) {
        const long long b6 = (long long)imgB * 6 + lane;
        out[b6] = myIB;
        out[(long long)B * 6 + b6] = mySB;
      }
    }
  }
}

extern "C" void kernel_launch(void* const* d_in, const int* in_sizes, int n_in,
                              void* d_out, int out_size, void* d_ws, size_t ws_size,
                              hipStream_t stream) {
  const float* x = (const float*)d_in[0];
  const int* coords = (const int*)d_in[1];
  float* out = (float*)d_out;
  const int B = in_sizes[0] / 196;
  const int nblk = (B + 7) / 8;
  appm_kernel<<<dim3(nblk), dim3(256), 0, stream>>>(x, coords, out, B);
}